// Round 1
// baseline (215.204 us; speedup 1.0000x reference)
//
#include <hip/hip_runtime.h>

typedef unsigned short u16;
typedef __attribute__((ext_vector_type(8))) short bf16x8;
typedef __attribute__((ext_vector_type(4))) float f32x4;

#define AS1C(p) ((const __attribute__((address_space(1))) void*)(p))
#define AS3(p)  ((__attribute__((address_space(3))) void*)(p))

__device__ __forceinline__ u16 f2bf(float f) {
    unsigned u = __float_as_uint(f);
    u += 0x7fffu + ((u >> 16) & 1u);   // RTNE
    return (u16)(u >> 16);
}

// ---------------------------------------------------------------------------
// LayerNorm over K=3072 fp32, write bf16 row to workspace A.
// One 256-thread block per row; each thread owns 3 float4 (12 elems).
// ---------------------------------------------------------------------------
__global__ __launch_bounds__(256) void ln_cast_kernel(
    const float* __restrict__ x, const float* __restrict__ w,
    const float* __restrict__ b, u16* __restrict__ A, int K)
{
    const int row = blockIdx.x;
    const int t = threadIdx.x;
    const float* xr = x + (size_t)row * K;

    float4 v[3];
#pragma unroll
    for (int i = 0; i < 3; ++i)
        v[i] = *(const float4*)&xr[(i * 256 + t) * 4];

    float s = 0.f;
#pragma unroll
    for (int i = 0; i < 3; ++i) s += v[i].x + v[i].y + v[i].z + v[i].w;
#pragma unroll
    for (int off = 32; off; off >>= 1) s += __shfl_down(s, off);

    __shared__ float red[8];
    const int wid = t >> 6, lane = t & 63;
    if (lane == 0) red[wid] = s;
    __syncthreads();
    const float mu = (red[0] + red[1] + red[2] + red[3]) * (1.0f / 3072.0f);

    float sq = 0.f;
#pragma unroll
    for (int i = 0; i < 3; ++i) {
        float dx = v[i].x - mu, dy = v[i].y - mu, dz = v[i].z - mu, dw = v[i].w - mu;
        sq += dx * dx + dy * dy + dz * dz + dw * dw;
    }
#pragma unroll
    for (int off = 32; off; off >>= 1) sq += __shfl_down(sq, off);
    if (lane == 0) red[4 + wid] = sq;
    __syncthreads();
    const float var = (red[4] + red[5] + red[6] + red[7]) * (1.0f / 3072.0f);
    const float inv = rsqrtf(var + 1e-5f);

#pragma unroll
    for (int i = 0; i < 3; ++i) {
        const int j = (i * 256 + t) * 4;
        const float4 wv = *(const float4*)&w[j];
        const float4 bv = *(const float4*)&b[j];
        ushort4 o;
        o.x = f2bf((v[i].x - mu) * inv * wv.x + bv.x);
        o.y = f2bf((v[i].y - mu) * inv * wv.y + bv.y);
        o.z = f2bf((v[i].z - mu) * inv * wv.z + bv.z);
        o.w = f2bf((v[i].w - mu) * inv * wv.w + bv.w);
        *(ushort4*)&A[(size_t)row * K + j] = o;
    }
}

// ---------------------------------------------------------------------------
// fp32 -> bf16 cast for W_patch [D,K] (row-major, stays [D,K] = B^T layout)
// ---------------------------------------------------------------------------
__global__ __launch_bounds__(256) void cast_w_kernel(
    const float* __restrict__ Wp, u16* __restrict__ Wb, int n4)
{
    const int i = blockIdx.x * 256 + threadIdx.x;
    if (i < n4) {
        const float4 v = ((const float4*)Wp)[i];
        ushort4 o;
        o.x = f2bf(v.x); o.y = f2bf(v.y); o.z = f2bf(v.z); o.w = f2bf(v.w);
        ((ushort4*)Wb)[i] = o;
    }
}

// ---------------------------------------------------------------------------
// Row 0: class_emb + class_pos
// ---------------------------------------------------------------------------
__global__ __launch_bounds__(256) void class_row_kernel(
    const float* __restrict__ ce, const float* __restrict__ cp,
    float* __restrict__ out, int D)
{
    const int i = blockIdx.x * 256 + threadIdx.x;
    if (i < D) out[i] = ce[i] + cp[i];
}

// ---------------------------------------------------------------------------
// bf16 GEMM C[n,d] = sum_k A[n,k] * W[d,k], fused pos epilogue, write rows 1..N
// 128x128 tile, BK=32, 4 waves (2x2 of 64x64), global_load_lds width-16.
// ---------------------------------------------------------------------------
__global__ __launch_bounds__(256, 2) void gemm_bt_fused_kernel(
    const u16* __restrict__ A, const u16* __restrict__ W,
    const float* __restrict__ bbox, const float* __restrict__ Wpos,
    const float* __restrict__ bpos, float* __restrict__ out,
    int M, int D, int K)
{
    __shared__ u16 As[128 * 32];
    __shared__ u16 Bs[128 * 32];

    const int t = threadIdx.x;
    const int brow = blockIdx.y * 128;
    const int bcol = blockIdx.x * 128;
    const int wid = t >> 6, lane = t & 63;
    const int wr = (wid >> 1) * 64;      // wave row offset in tile
    const int wc = (wid & 1) * 64;       // wave col offset in tile

    // staging source coords: thread t covers (row=t/4, col=(t%4)*8) and +64 rows
    const int srow = t >> 2;
    const int scol = (t & 3) * 8;
    const u16* gA = A + (size_t)(brow + srow) * K + scol;
    const u16* gB = W + (size_t)(bcol + srow) * K + scol;

    f32x4 acc[4][4] = {};

    const int nk = K >> 5;
    for (int kt = 0; kt < nk; ++kt) {
        const int k0 = kt << 5;
        __builtin_amdgcn_global_load_lds(AS1C(gA + k0),                   AS3(&As[t * 8]),        16, 0, 0);
        __builtin_amdgcn_global_load_lds(AS1C(gA + (size_t)64 * K + k0),  AS3(&As[2048 + t * 8]), 16, 0, 0);
        __builtin_amdgcn_global_load_lds(AS1C(gB + k0),                   AS3(&Bs[t * 8]),        16, 0, 0);
        __builtin_amdgcn_global_load_lds(AS1C(gB + (size_t)64 * K + k0),  AS3(&Bs[2048 + t * 8]), 16, 0, 0);
        __syncthreads();

        bf16x8 af[4], bfr[4];
        const int fr = lane & 15;          // fragment row/col within 16
        const int kq = (lane >> 4) * 8;    // k offset within 32
#pragma unroll
        for (int m = 0; m < 4; ++m)
            af[m] = *(const bf16x8*)&As[(wr + m * 16 + fr) * 32 + kq];
#pragma unroll
        for (int n = 0; n < 4; ++n)
            bfr[n] = *(const bf16x8*)&Bs[(wc + n * 16 + fr) * 32 + kq];

#pragma unroll
        for (int m = 0; m < 4; ++m)
#pragma unroll
            for (int n = 0; n < 4; ++n)
                acc[m][n] = __builtin_amdgcn_mfma_f32_16x16x32_bf16(af[m], bfr[n], acc[m][n], 0, 0, 0);
        __syncthreads();
    }

    // epilogue: C/D layout col = lane&15, row = (lane>>4)*4 + r
    const int crow0 = brow + wr + ((lane >> 4) << 2);
    const int ccol = bcol + wc + (lane & 15);

    float4 wp[4];
    float bp[4];
#pragma unroll
    for (int n = 0; n < 4; ++n) {
        const int gc = ccol + n * 16;
        wp[n] = *(const float4*)&Wpos[gc * 4];
        bp[n] = bpos[gc];
    }

#pragma unroll
    for (int m = 0; m < 4; ++m) {
#pragma unroll
        for (int r = 0; r < 4; ++r) {
            const int gr = crow0 + m * 16 + r;
            const float4 bb = *(const float4*)&bbox[(size_t)gr * 4];
            float* orow = out + (size_t)(gr + 1) * D;
#pragma unroll
            for (int n = 0; n < 4; ++n) {
                const float pos = bp[n] + bb.x * wp[n].x + bb.y * wp[n].y
                                        + bb.z * wp[n].z + bb.w * wp[n].w;
                orow[ccol + n * 16] = acc[m][n][r] + pos;
            }
        }
    }
}

// ---------------------------------------------------------------------------
extern "C" void kernel_launch(void* const* d_in, const int* in_sizes, int n_in,
                              void* d_out, int out_size, void* d_ws, size_t ws_size,
                              hipStream_t stream)
{
    const float* patches   = (const float*)d_in[0];
    const float* bbox      = (const float*)d_in[1];
    const float* ln1_w     = (const float*)d_in[2];
    const float* ln1_b     = (const float*)d_in[3];
    const float* W_patch   = (const float*)d_in[4];
    const float* class_emb = (const float*)d_in[5];
    const float* W_pos     = (const float*)d_in[6];
    const float* b_pos     = (const float*)d_in[7];
    const float* class_pos = (const float*)d_in[8];
    float* out = (float*)d_out;

    const int N = in_sizes[1] / 4;   // 16384
    const int K = in_sizes[2];       // 3072
    const int D = in_sizes[7];       // 1024

    u16* Abf = (u16*)d_ws;                       // [N,K] bf16
    u16* Wbf = Abf + (size_t)N * K;              // [D,K] bf16

    ln_cast_kernel<<<N, 256, 0, stream>>>(patches, ln1_w, ln1_b, Abf, K);

    const int n4 = (D * K) / 4;
    cast_w_kernel<<<(n4 + 255) / 256, 256, 0, stream>>>(W_patch, Wbf, n4);

    class_row_kernel<<<(D + 255) / 256, 256, 0, stream>>>(class_emb, class_pos, out, D);

    dim3 grid(D / 128, N / 128);
    gemm_bt_fused_kernel<<<grid, 256, 0, stream>>>(Abf, Wbf, bbox, W_pos, b_pos, out, N, D, K);
}

// Round 2
// 169.211 us; speedup vs baseline: 1.2718x; 1.2718x over previous
//
#include <hip/hip_runtime.h>

typedef unsigned short u16;
typedef __attribute__((ext_vector_type(8))) short bf16x8;
typedef __attribute__((ext_vector_type(4))) float f32x4;

#define AS1C(p) ((const __attribute__((address_space(1))) void*)(p))
#define AS3(p)  ((__attribute__((address_space(3))) void*)(p))

__device__ __forceinline__ u16 f2bf(float f) {
    unsigned u = __float_as_uint(f);
    u += 0x7fffu + ((u >> 16) & 1u);   // RTNE
    return (u16)(u >> 16);
}

// ---------------------------------------------------------------------------
// LayerNorm over K=3072 fp32, write bf16 row to workspace A. (~50us, BW-bound)
// ---------------------------------------------------------------------------
__global__ __launch_bounds__(256) void ln_cast_kernel(
    const float* __restrict__ x, const float* __restrict__ w,
    const float* __restrict__ b, u16* __restrict__ A, int K)
{
    const int row = blockIdx.x;
    const int t = threadIdx.x;
    const float* xr = x + (size_t)row * K;

    float4 v[3];
#pragma unroll
    for (int i = 0; i < 3; ++i)
        v[i] = *(const float4*)&xr[(i * 256 + t) * 4];

    float s = 0.f;
#pragma unroll
    for (int i = 0; i < 3; ++i) s += v[i].x + v[i].y + v[i].z + v[i].w;
#pragma unroll
    for (int off = 32; off; off >>= 1) s += __shfl_down(s, off);

    __shared__ float red[8];
    const int wid = t >> 6, lane = t & 63;
    if (lane == 0) red[wid] = s;
    __syncthreads();
    const float mu = (red[0] + red[1] + red[2] + red[3]) * (1.0f / 3072.0f);

    float sq = 0.f;
#pragma unroll
    for (int i = 0; i < 3; ++i) {
        float dx = v[i].x - mu, dy = v[i].y - mu, dz = v[i].z - mu, dw = v[i].w - mu;
        sq += dx * dx + dy * dy + dz * dz + dw * dw;
    }
#pragma unroll
    for (int off = 32; off; off >>= 1) sq += __shfl_down(sq, off);
    if (lane == 0) red[4 + wid] = sq;
    __syncthreads();
    const float var = (red[4] + red[5] + red[6] + red[7]) * (1.0f / 3072.0f);
    const float inv = rsqrtf(var + 1e-5f);

#pragma unroll
    for (int i = 0; i < 3; ++i) {
        const int j = (i * 256 + t) * 4;
        const float4 wv = *(const float4*)&w[j];
        const float4 bv = *(const float4*)&b[j];
        ushort4 o;
        o.x = f2bf((v[i].x - mu) * inv * wv.x + bv.x);
        o.y = f2bf((v[i].y - mu) * inv * wv.y + bv.y);
        o.z = f2bf((v[i].z - mu) * inv * wv.z + bv.z);
        o.w = f2bf((v[i].w - mu) * inv * wv.w + bv.w);
        *(ushort4*)&A[(size_t)row * K + j] = o;
    }
}

__global__ __launch_bounds__(256) void cast_w_kernel(
    const float* __restrict__ Wp, u16* __restrict__ Wb, int n4)
{
    const int i = blockIdx.x * 256 + threadIdx.x;
    if (i < n4) {
        const float4 v = ((const float4*)Wp)[i];
        ushort4 o;
        o.x = f2bf(v.x); o.y = f2bf(v.y); o.z = f2bf(v.z); o.w = f2bf(v.w);
        ((ushort4*)Wb)[i] = o;
    }
}

__global__ __launch_bounds__(256) void class_row_kernel(
    const float* __restrict__ ce, const float* __restrict__ cp,
    float* __restrict__ out, int D)
{
    const int i = blockIdx.x * 256 + threadIdx.x;
    if (i < D) out[i] = ce[i] + cp[i];
}

// ---------------------------------------------------------------------------
// 256x256 8-phase bf16 GEMM: C[n,d] = sum_k A[n,k]*W[d,k], fused pos epilogue.
// BK=64, 8 waves (2Mx4N), per-wave 128x64, LDS 128KB (2 buf x (A 32K + B 32K)),
// st_16x32 swizzle, counted vmcnt, setprio around MFMA, XCD-bijective swizzle.
// Phase = (M-half, K-half) quadrant: 16 MFMA, 8 ds_read_b128, 2 global_load_lds.
// ---------------------------------------------------------------------------
#define STG_A(BUFOFS, R0, T_) \
    __builtin_amdgcn_global_load_lds(AS1C(aS + (size_t)(R0) * 3072 + (T_) * 64), \
                                     AS3(dA + (BUFOFS) + (R0) * 128), 16, 0, 0)
#define STG_B(BUFOFS, R0, T_) \
    __builtin_amdgcn_global_load_lds(AS1C(bS + (size_t)(R0) * 3072 + (T_) * 64), \
                                     AS3(dB + (BUFOFS) + (R0) * 128), 16, 0, 0)

#define MFMA(d, a, b) d = __builtin_amdgcn_mfma_f32_16x16x32_bf16(a, b, d, 0, 0, 0)

#define PHASE(BUF, MH, CK, STG, WT) do {                                          \
    const char* Lb = L + (BUF);                                                   \
    bf16x8 a0 = *(const bf16x8*)(Lb + aRowBase + (MH)*8192 + 0*2048 + (CK));      \
    bf16x8 a1 = *(const bf16x8*)(Lb + aRowBase + (MH)*8192 + 1*2048 + (CK));      \
    bf16x8 a2 = *(const bf16x8*)(Lb + aRowBase + (MH)*8192 + 2*2048 + (CK));      \
    bf16x8 a3 = *(const bf16x8*)(Lb + aRowBase + (MH)*8192 + 3*2048 + (CK));      \
    bf16x8 b0 = *(const bf16x8*)(Lb + bRowBase + 0*2048 + (CK));                  \
    bf16x8 b1 = *(const bf16x8*)(Lb + bRowBase + 1*2048 + (CK));                  \
    bf16x8 b2 = *(const bf16x8*)(Lb + bRowBase + 2*2048 + (CK));                  \
    bf16x8 b3 = *(const bf16x8*)(Lb + bRowBase + 3*2048 + (CK));                  \
    STG;                                                                          \
    __builtin_amdgcn_s_barrier();                                                 \
    asm volatile("s_waitcnt lgkmcnt(0)" ::: "memory");                            \
    __builtin_amdgcn_s_setprio(1);                                                \
    MFMA(acc[(MH)*4+0][0], a0, b0); MFMA(acc[(MH)*4+0][1], a0, b1);               \
    MFMA(acc[(MH)*4+0][2], a0, b2); MFMA(acc[(MH)*4+0][3], a0, b3);               \
    MFMA(acc[(MH)*4+1][0], a1, b0); MFMA(acc[(MH)*4+1][1], a1, b1);               \
    MFMA(acc[(MH)*4+1][2], a1, b2); MFMA(acc[(MH)*4+1][3], a1, b3);               \
    MFMA(acc[(MH)*4+2][0], a2, b0); MFMA(acc[(MH)*4+2][1], a2, b1);               \
    MFMA(acc[(MH)*4+2][2], a2, b2); MFMA(acc[(MH)*4+2][3], a2, b3);               \
    MFMA(acc[(MH)*4+3][0], a3, b0); MFMA(acc[(MH)*4+3][1], a3, b1);               \
    MFMA(acc[(MH)*4+3][2], a3, b2); MFMA(acc[(MH)*4+3][3], a3, b3);               \
    __builtin_amdgcn_s_setprio(0);                                                \
    WT;                                                                           \
    __builtin_amdgcn_s_barrier();                                                 \
} while (0)

__global__ __launch_bounds__(512, 2) void gemm_256_8ph_kernel(
    const u16* __restrict__ A, const u16* __restrict__ W,
    const float* __restrict__ bbox, const float* __restrict__ Wpos,
    const float* __restrict__ bpos, float* __restrict__ out,
    int D)
{
    __shared__ __align__(16) char lds[131072];
    const char* L = (const char*)lds;
    const int K = 3072;
    const int NK = 48;                     // K / 64

    // XCD-bijective swizzle: 256 blocks, 8 XCDs, 32 contiguous tiles per XCD.
    const int bid = blockIdx.x;
    const int swb = (bid & 7) * 32 + (bid >> 3);
    const int bx = swb & 3;                // D/256 = 4
    const int by = swb >> 2;               // M/256 = 64
    const int brow = by * 256;
    const int bcol = bx * 256;

    const int t = threadIdx.x;
    const int wid = t >> 6, lane = t & 63;
    const int wm = wid >> 2;               // 0..1
    const int wn = wid & 3;                // 0..3
    const int fr = lane & 15;
    const int kq16 = ((lane >> 4) & 3) * 16;
    const int xorb = (fr & 4) << 3;        // st_16x32: byte ^= ((byte>>9)&1)<<5
    const int aRowBase = (wm * 128 + fr) * 128;
    const int bRowBase = 32768 + (wn * 64 + fr) * 128;
    const int ck0 = kq16 ^ xorb;
    const int ck1 = (64 + kq16) ^ xorb;

    // staging: pre-swizzled global source, linear LDS dest (t*16 bytes)
    const int sw = (t * 16) ^ (t & 32);
    const int srow = sw >> 7;              // 0..63
    const int scol = (sw & 127) >> 1;      // bf16 col, multiple of 8
    const u16* aS = A + (size_t)(brow + srow) * K + scol;
    const u16* bS = W + (size_t)(bcol + srow) * K + scol;
    char* dA = (char*)lds + t * 16;
    char* dB = (char*)lds + 32768 + t * 16;

    f32x4 acc[8][4] = {};

    // prologue: tile0 full (8), tile1 A-Mh0 (2); wait for tile0, keep 2 in flight
    STG_A(0, 0, 0);   STG_A(0, 64, 0);  STG_A(0, 128, 0); STG_A(0, 192, 0);
    STG_B(0, 0, 0);   STG_B(0, 64, 0);  STG_B(0, 128, 0); STG_B(0, 192, 0);
    STG_A(65536, 0, 1); STG_A(65536, 128, 1);
    asm volatile("s_waitcnt vmcnt(2)" ::: "memory");
    __builtin_amdgcn_s_barrier();

    for (int T = 0; T < NK; T += 2) {
        const bool more = (T + 2) < NK;
        // P1: tile T (buf0) Mh0,k0 | stage A(T+1) Mh1 -> buf1
        PHASE(0, 0, ck0, { STG_A(65536, 64, T + 1); STG_A(65536, 192, T + 1); }, ((void)0));
        // P2: Mh1,k0 | stage B(T+1) lo -> buf1
        PHASE(0, 1, ck0, { STG_B(65536, 0, T + 1); STG_B(65536, 64, T + 1); }, ((void)0));
        // P3: Mh0,k1 | stage B(T+1) hi -> buf1
        PHASE(0, 0, ck1, { STG_B(65536, 128, T + 1); STG_B(65536, 192, T + 1); }, ((void)0));
        // P4: Mh1,k1 | stage A(T+2) Mh0 -> buf0 (dead after P3) | wait tile T+1 ready
        PHASE(0, 1, ck1,
              { if (more) { STG_A(0, 0, T + 2); STG_A(0, 128, T + 2); } },
              { if (more) asm volatile("s_waitcnt vmcnt(2)" ::: "memory");
                else      asm volatile("s_waitcnt vmcnt(0)" ::: "memory"); });
        // P5: tile T+1 (buf1) Mh0,k0 | stage A(T+2) Mh1
        PHASE(65536, 0, ck0, { if (more) { STG_A(0, 64, T + 2); STG_A(0, 192, T + 2); } }, ((void)0));
        // P6: Mh1,k0 | stage B(T+2) lo (buf0 B dead after P4)
        PHASE(65536, 1, ck0, { if (more) { STG_B(0, 0, T + 2); STG_B(0, 64, T + 2); } }, ((void)0));
        // P7: Mh0,k1 | stage B(T+2) hi
        PHASE(65536, 0, ck1, { if (more) { STG_B(0, 128, T + 2); STG_B(0, 192, T + 2); } }, ((void)0));
        // P8: Mh1,k1 | stage A(T+3) Mh0 -> buf1 (dead after P7) | wait tile T+2 ready
        PHASE(65536, 1, ck1,
              { if (more) { STG_A(65536, 0, T + 3); STG_A(65536, 128, T + 3); } },
              { asm volatile("s_waitcnt vmcnt(2)" ::: "memory"); });
    }

    // epilogue: C/D layout col = lane&15, row = (lane>>4)*4 + r; fused pos-proj
    const int crow0 = brow + wm * 128 + ((lane >> 4) & 3) * 4;
    const int ccol = bcol + wn * 64 + fr;

    float4 wp[4];
    float bp[4];
#pragma unroll
    for (int n = 0; n < 4; ++n) {
        const int gc = ccol + n * 16;
        wp[n] = *(const float4*)&Wpos[gc * 4];
        bp[n] = bpos[gc];
    }

#pragma unroll
    for (int mi = 0; mi < 8; ++mi) {
#pragma unroll
        for (int r = 0; r < 4; ++r) {
            const int gr = crow0 + mi * 16 + r;
            const float4 bb = *(const float4*)&bbox[(size_t)gr * 4];
            float* orow = out + (size_t)(gr + 1) * D;
#pragma unroll
            for (int n = 0; n < 4; ++n) {
                const float pos = bp[n] + bb.x * wp[n].x + bb.y * wp[n].y
                                        + bb.z * wp[n].z + bb.w * wp[n].w;
                orow[ccol + n * 16] = acc[mi][n][r] + pos;
            }
        }
    }
}

// ---------------------------------------------------------------------------
extern "C" void kernel_launch(void* const* d_in, const int* in_sizes, int n_in,
                              void* d_out, int out_size, void* d_ws, size_t ws_size,
                              hipStream_t stream)
{
    const float* patches   = (const float*)d_in[0];
    const float* bbox      = (const float*)d_in[1];
    const float* ln1_w     = (const float*)d_in[2];
    const float* ln1_b     = (const float*)d_in[3];
    const float* W_patch   = (const float*)d_in[4];
    const float* class_emb = (const float*)d_in[5];
    const float* W_pos     = (const float*)d_in[6];
    const float* b_pos     = (const float*)d_in[7];
    const float* class_pos = (const float*)d_in[8];
    float* out = (float*)d_out;

    const int N = in_sizes[1] / 4;   // 16384
    const int K = in_sizes[2];       // 3072
    const int D = in_sizes[7];       // 1024

    u16* Abf = (u16*)d_ws;                       // [N,K] bf16
    u16* Wbf = Abf + (size_t)N * K;              // [D,K] bf16

    ln_cast_kernel<<<N, 256, 0, stream>>>(patches, ln1_w, ln1_b, Abf, K);

    const int n4 = (D * K) / 4;
    cast_w_kernel<<<(n4 + 255) / 256, 256, 0, stream>>>(W_patch, Wbf, n4);

    class_row_kernel<<<(D + 255) / 256, 256, 0, stream>>>(class_emb, class_pos, out, D);

    const int nblk = (N / 256) * (D / 256);      // 64 * 4 = 256
    gemm_256_8ph_kernel<<<nblk, 512, 0, stream>>>(Abf, Wbf, bbox, W_pos, b_pos, out, D);
}

// Round 3
// 158.268 us; speedup vs baseline: 1.3597x; 1.0691x over previous
//
#include <hip/hip_runtime.h>

typedef unsigned short u16;
typedef __attribute__((ext_vector_type(8))) short bf16x8;
typedef __attribute__((ext_vector_type(4))) float f32x4;

#define AS1C(p) ((const __attribute__((address_space(1))) void*)(p))
#define AS3(p)  ((__attribute__((address_space(3))) void*)(p))

__device__ __forceinline__ u16 f2bf(float f) {
    unsigned u = __float_as_uint(f);
    u += 0x7fffu + ((u >> 16) & 1u);   // RTNE
    return (u16)(u >> 16);
}

// ---------------------------------------------------------------------------
// LayerNorm over K=3072 fp32, write bf16 row to workspace A. (~50us, BW-bound)
// ---------------------------------------------------------------------------
__global__ __launch_bounds__(256) void ln_cast_kernel(
    const float* __restrict__ x, const float* __restrict__ w,
    const float* __restrict__ b, u16* __restrict__ A, int K)
{
    const int row = blockIdx.x;
    const int t = threadIdx.x;
    const float* xr = x + (size_t)row * K;

    float4 v[3];
#pragma unroll
    for (int i = 0; i < 3; ++i)
        v[i] = *(const float4*)&xr[(i * 256 + t) * 4];

    float s = 0.f;
#pragma unroll
    for (int i = 0; i < 3; ++i) s += v[i].x + v[i].y + v[i].z + v[i].w;
#pragma unroll
    for (int off = 32; off; off >>= 1) s += __shfl_down(s, off);

    __shared__ float red[8];
    const int wid = t >> 6, lane = t & 63;
    if (lane == 0) red[wid] = s;
    __syncthreads();
    const float mu = (red[0] + red[1] + red[2] + red[3]) * (1.0f / 3072.0f);

    float sq = 0.f;
#pragma unroll
    for (int i = 0; i < 3; ++i) {
        float dx = v[i].x - mu, dy = v[i].y - mu, dz = v[i].z - mu, dw = v[i].w - mu;
        sq += dx * dx + dy * dy + dz * dz + dw * dw;
    }
#pragma unroll
    for (int off = 32; off; off >>= 1) sq += __shfl_down(sq, off);
    if (lane == 0) red[4 + wid] = sq;
    __syncthreads();
    const float var = (red[4] + red[5] + red[6] + red[7]) * (1.0f / 3072.0f);
    const float inv = rsqrtf(var + 1e-5f);

#pragma unroll
    for (int i = 0; i < 3; ++i) {
        const int j = (i * 256 + t) * 4;
        const float4 wv = *(const float4*)&w[j];
        const float4 bv = *(const float4*)&b[j];
        ushort4 o;
        o.x = f2bf((v[i].x - mu) * inv * wv.x + bv.x);
        o.y = f2bf((v[i].y - mu) * inv * wv.y + bv.y);
        o.z = f2bf((v[i].z - mu) * inv * wv.z + bv.z);
        o.w = f2bf((v[i].w - mu) * inv * wv.w + bv.w);
        *(ushort4*)&A[(size_t)row * K + j] = o;
    }
}

__global__ __launch_bounds__(256) void cast_w_kernel(
    const float* __restrict__ Wp, u16* __restrict__ Wb, int n4)
{
    const int i = blockIdx.x * 256 + threadIdx.x;
    if (i < n4) {
        const float4 v = ((const float4*)Wp)[i];
        ushort4 o;
        o.x = f2bf(v.x); o.y = f2bf(v.y); o.z = f2bf(v.z); o.w = f2bf(v.w);
        ((ushort4*)Wb)[i] = o;
    }
}

__global__ __launch_bounds__(256) void class_row_kernel(
    const float* __restrict__ ce, const float* __restrict__ cp,
    float* __restrict__ out, int D)
{
    const int i = blockIdx.x * 256 + threadIdx.x;
    if (i < D) out[i] = ce[i] + cp[i];
}

// ---------------------------------------------------------------------------
// 256x256 8-phase bf16 GEMM: C[n,d] = sum_k A[n,k]*W[d,k], fused pos epilogue.
// BK=64, 8 waves (2Mx4N), per-wave 128x64, LDS 128KB (2 buf x (A 32K + B 32K)),
// FULL 3-bit XOR swizzle (byte ^= (row&7)<<4), counted vmcnt, setprio,
// XCD-bijective block swizzle.
// ---------------------------------------------------------------------------
#define STG_A(BUFOFS, R0, T_) \
    __builtin_amdgcn_global_load_lds(AS1C(aS + (size_t)(R0) * 3072 + (T_) * 64), \
                                     AS3(dA + (BUFOFS) + (R0) * 128), 16, 0, 0)
#define STG_B(BUFOFS, R0, T_) \
    __builtin_amdgcn_global_load_lds(AS1C(bS + (size_t)(R0) * 3072 + (T_) * 64), \
                                     AS3(dB + (BUFOFS) + (R0) * 128), 16, 0, 0)

#define MFMA(d, a, b) d = __builtin_amdgcn_mfma_f32_16x16x32_bf16(a, b, d, 0, 0, 0)

#define PHASE(BUF, MH, CK, STG, WT) do {                                          \
    const char* Lb = L + (BUF);                                                   \
    bf16x8 a0 = *(const bf16x8*)(Lb + aRowBase + (MH)*8192 + 0*2048 + (CK));      \
    bf16x8 a1 = *(const bf16x8*)(Lb + aRowBase + (MH)*8192 + 1*2048 + (CK));      \
    bf16x8 a2 = *(const bf16x8*)(Lb + aRowBase + (MH)*8192 + 2*2048 + (CK));      \
    bf16x8 a3 = *(const bf16x8*)(Lb + aRowBase + (MH)*8192 + 3*2048 + (CK));      \
    bf16x8 b0 = *(const bf16x8*)(Lb + bRowBase + 0*2048 + (CK));                  \
    bf16x8 b1 = *(const bf16x8*)(Lb + bRowBase + 1*2048 + (CK));                  \
    bf16x8 b2 = *(const bf16x8*)(Lb + bRowBase + 2*2048 + (CK));                  \
    bf16x8 b3 = *(const bf16x8*)(Lb + bRowBase + 3*2048 + (CK));                  \
    STG;                                                                          \
    __builtin_amdgcn_s_barrier();                                                 \
    asm volatile("s_waitcnt lgkmcnt(0)" ::: "memory");                            \
    __builtin_amdgcn_s_setprio(1);                                                \
    MFMA(acc[(MH)*4+0][0], a0, b0); MFMA(acc[(MH)*4+0][1], a0, b1);               \
    MFMA(acc[(MH)*4+0][2], a0, b2); MFMA(acc[(MH)*4+0][3], a0, b3);               \
    MFMA(acc[(MH)*4+1][0], a1, b0); MFMA(acc[(MH)*4+1][1], a1, b1);               \
    MFMA(acc[(MH)*4+1][2], a1, b2); MFMA(acc[(MH)*4+1][3], a1, b3);               \
    MFMA(acc[(MH)*4+2][0], a2, b0); MFMA(acc[(MH)*4+2][1], a2, b1);               \
    MFMA(acc[(MH)*4+2][2], a2, b2); MFMA(acc[(MH)*4+2][3], a2, b3);               \
    MFMA(acc[(MH)*4+3][0], a3, b0); MFMA(acc[(MH)*4+3][1], a3, b1);               \
    MFMA(acc[(MH)*4+3][2], a3, b2); MFMA(acc[(MH)*4+3][3], a3, b3);               \
    __builtin_amdgcn_s_setprio(0);                                                \
    WT;                                                                           \
    __builtin_amdgcn_s_barrier();                                                 \
} while (0)

__global__ __launch_bounds__(512, 2) void gemm_256_8ph_kernel(
    const u16* __restrict__ A, const u16* __restrict__ W,
    const float* __restrict__ bbox, const float* __restrict__ Wpos,
    const float* __restrict__ bpos, float* __restrict__ out,
    int D)
{
    __shared__ __align__(16) char lds[131072];
    const char* L = (const char*)lds;
    const int K = 3072;
    const int NK = 48;                     // K / 64

    // XCD-bijective swizzle: 256 blocks, 8 XCDs, 32 contiguous tiles per XCD.
    const int bid = blockIdx.x;
    const int swb = (bid & 7) * 32 + (bid >> 3);
    const int bx = swb & 3;                // D/256 = 4
    const int by = swb >> 2;               // M/256 = 64
    const int brow = by * 256;
    const int bcol = bx * 256;

    const int t = threadIdx.x;
    const int wid = t >> 6, lane = t & 63;
    const int wm = wid >> 2;               // 0..1
    const int wn = wid & 3;                // 0..3
    const int fr = lane & 15;
    const int kq16 = ((lane >> 4) & 3) * 16;
    // full 3-bit swizzle: stored byte col = c ^ ((row&7)<<4); row&7 == fr&7
    const int xorb = (fr & 7) << 4;
    const int aRowBase = (wm * 128 + fr) * 128;
    const int bRowBase = 32768 + (wn * 64 + fr) * 128;
    const int ck0 = kq16 ^ xorb;
    const int ck1 = (64 + kq16) ^ xorb;

    // staging: linear LDS dest (t*16 B), pre-swizzled global source.
    // dest row (within 64-row chunk) = t>>3, slot = t&7;
    // source 16B-slot = (t&7) ^ ((t>>3)&7)   (R0 is a multiple of 64 -> row&7 invariant)
    const int srow = t >> 3;
    const int scol = ((t & 7) ^ ((t >> 3) & 7)) * 8;   // bf16 units
    const u16* aS = A + (size_t)(brow + srow) * K + scol;
    const u16* bS = W + (size_t)(bcol + srow) * K + scol;
    char* dA = (char*)lds + t * 16;
    char* dB = (char*)lds + 32768 + t * 16;

    f32x4 acc[8][4] = {};

    // prologue: tile0 full (8), tile1 A-Mh0 (2); wait for tile0, keep 2 in flight
    STG_A(0, 0, 0);   STG_A(0, 64, 0);  STG_A(0, 128, 0); STG_A(0, 192, 0);
    STG_B(0, 0, 0);   STG_B(0, 64, 0);  STG_B(0, 128, 0); STG_B(0, 192, 0);
    STG_A(65536, 0, 1); STG_A(65536, 128, 1);
    asm volatile("s_waitcnt vmcnt(2)" ::: "memory");
    __builtin_amdgcn_s_barrier();

    for (int T = 0; T < NK; T += 2) {
        const bool more = (T + 2) < NK;
        // P1: tile T (buf0) Mh0,k0 | stage A(T+1) Mh1 -> buf1
        PHASE(0, 0, ck0, { STG_A(65536, 64, T + 1); STG_A(65536, 192, T + 1); }, ((void)0));
        // P2: Mh1,k0 | stage B(T+1) lo -> buf1
        PHASE(0, 1, ck0, { STG_B(65536, 0, T + 1); STG_B(65536, 64, T + 1); }, ((void)0));
        // P3: Mh0,k1 | stage B(T+1) hi -> buf1
        PHASE(0, 0, ck1, { STG_B(65536, 128, T + 1); STG_B(65536, 192, T + 1); }, ((void)0));
        // P4: Mh1,k1 | stage A(T+2) Mh0 -> buf0 (dead after P3) | wait tile T+1 ready
        PHASE(0, 1, ck1,
              { if (more) { STG_A(0, 0, T + 2); STG_A(0, 128, T + 2); } },
              { if (more) asm volatile("s_waitcnt vmcnt(2)" ::: "memory");
                else      asm volatile("s_waitcnt vmcnt(0)" ::: "memory"); });
        // P5: tile T+1 (buf1) Mh0,k0 | stage A(T+2) Mh1
        PHASE(65536, 0, ck0, { if (more) { STG_A(0, 64, T + 2); STG_A(0, 192, T + 2); } }, ((void)0));
        // P6: Mh1,k0 | stage B(T+2) lo (buf0 B dead after P4)
        PHASE(65536, 1, ck0, { if (more) { STG_B(0, 0, T + 2); STG_B(0, 64, T + 2); } }, ((void)0));
        // P7: Mh0,k1 | stage B(T+2) hi
        PHASE(65536, 0, ck1, { if (more) { STG_B(0, 128, T + 2); STG_B(0, 192, T + 2); } }, ((void)0));
        // P8: Mh1,k1 | stage A(T+3) Mh0 -> buf1 (dead after P7) | wait tile T+2 ready
        PHASE(65536, 1, ck1,
              { if (more) { STG_A(65536, 0, T + 3); STG_A(65536, 128, T + 3); } },
              { asm volatile("s_waitcnt vmcnt(2)" ::: "memory"); });
    }

    // epilogue: C/D layout col = lane&15, row = (lane>>4)*4 + r; fused pos-proj
    const int crow0 = brow + wm * 128 + ((lane >> 4) & 3) * 4;
    const int ccol = bcol + wn * 64 + fr;

    float4 wp[4];
    float bp[4];
#pragma unroll
    for (int n = 0; n < 4; ++n) {
        const int gc = ccol + n * 16;
        wp[n] = *(const float4*)&Wpos[gc * 4];
        bp[n] = bpos[gc];
    }

#pragma unroll
    for (int mi = 0; mi < 8; ++mi) {
#pragma unroll
        for (int r = 0; r < 4; ++r) {
            const int gr = crow0 + mi * 16 + r;
            const float4 bb = *(const float4*)&bbox[(size_t)gr * 4];
            float* orow = out + (size_t)(gr + 1) * D;
#pragma unroll
            for (int n = 0; n < 4; ++n) {
                const float pos = bp[n] + bb.x * wp[n].x + bb.y * wp[n].y
                                        + bb.z * wp[n].z + bb.w * wp[n].w;
                orow[ccol + n * 16] = acc[mi][n][r] + pos;
            }
        }
    }
}

// ---------------------------------------------------------------------------
extern "C" void kernel_launch(void* const* d_in, const int* in_sizes, int n_in,
                              void* d_out, int out_size, void* d_ws, size_t ws_size,
                              hipStream_t stream)
{
    const float* patches   = (const float*)d_in[0];
    const float* bbox      = (const float*)d_in[1];
    const float* ln1_w     = (const float*)d_in[2];
    const float* ln1_b     = (const float*)d_in[3];
    const float* W_patch   = (const float*)d_in[4];
    const float* class_emb = (const float*)d_in[5];
    const float* W_pos     = (const float*)d_in[6];
    const float* b_pos     = (const float*)d_in[7];
    const float* class_pos = (const float*)d_in[8];
    float* out = (float*)d_out;

    const int N = in_sizes[1] / 4;   // 16384
    const int K = in_sizes[2];       // 3072
    const int D = in_sizes[7];       // 1024

    u16* Abf = (u16*)d_ws;                       // [N,K] bf16
    u16* Wbf = Abf + (size_t)N * K;              // [D,K] bf16

    ln_cast_kernel<<<N, 256, 0, stream>>>(patches, ln1_w, ln1_b, Abf, K);

    const int n4 = (D * K) / 4;
    cast_w_kernel<<<(n4 + 255) / 256, 256, 0, stream>>>(W_patch, Wbf, n4);

    class_row_kernel<<<(D + 255) / 256, 256, 0, stream>>>(class_emb, class_pos, out, D);

    const int nblk = (N / 256) * (D / 256);      // 64 * 4 = 256
    gemm_256_8ph_kernel<<<nblk, 512, 0, stream>>>(Abf, Wbf, bbox, W_pos, b_pos, out, D);
}